// Round 1
// baseline (645.374 us; speedup 1.0000x reference)
//
#include <hip/hip_runtime.h>

#define NN   100000
#define NE   1200000
#define MT   (NE + NN)      // edges + self loops
#define INF_ 128
#define CIN  112            // IN - POS
#define HH   4
#define HD   64             // H * OUT
#define NEG_SLOPE 0.2f

// K1: content = x[:, :112] @ W  (N x 64), plus per-node scores
//   si[n,h] = sum_d content*att[h,d]    + sum_p pos*pos_att[h,p]
//   sj[n,h] = sum_d content*att[h,16+d] + sum_p pos*pos_att[h,16+p]
__global__ __launch_bounds__(256) void k_content(
    const float* __restrict__ x, const float* __restrict__ W,
    const float* __restrict__ att, const float* __restrict__ pos_att,
    float* __restrict__ content, float* __restrict__ si, float* __restrict__ sj)
{
    __shared__ float Wl[CIN * HD];    // 28672 B
    __shared__ float xs[4][INF_];     // 2048 B
    const int t = threadIdx.x;
    for (int i = t; i < CIN * HD; i += 256) Wl[i] = W[i];
    const int sub = t >> 6;           // node within chunk (one wave per node)
    const int o   = t & 63;           // output column = h*16+d
    const int h = o >> 4, d = o & 15;
    const float att_i = att[h * 32 + d];
    const float att_j = att[h * 32 + 16 + d];
    const float pat_i = pos_att[h * 32 + d];
    const float pat_j = pos_att[h * 32 + 16 + d];
    const int nchunk = NN / 4;        // 100000 % 4 == 0
    for (int chunk = blockIdx.x; chunk < nchunk; chunk += gridDim.x) {
        const int n0 = chunk * 4;
        __syncthreads();
        for (int i = t; i < 4 * INF_; i += 256)
            xs[i >> 7][i & 127] = x[(n0 + (i >> 7)) * INF_ + (i & 127)];
        __syncthreads();
        const int n = n0 + sub;
        float acc = 0.f;
        const float* xr = xs[sub];
        #pragma unroll
        for (int k = 0; k < CIN; ++k) acc = fmaf(xr[k], Wl[k * HD + o], acc);
        content[n * HD + o] = acc;
        const float p = xr[CIN + d];
        float v1 = fmaf(acc, att_i, p * pat_i);
        float v2 = fmaf(acc, att_j, p * pat_j);
        #pragma unroll
        for (int m = 8; m >= 1; m >>= 1) {
            v1 += __shfl_xor(v1, m);
            v2 += __shfl_xor(v2, m);
        }
        if (d == 0) { si[n * HH + h] = v1; sj[n * HH + h] = v2; }
    }
}

// K2: out = bias (accumulation base)
__global__ __launch_bounds__(256) void k_init_out(
    const float* __restrict__ bias, float* __restrict__ out)
{
    const int total = NN * HD;
    for (int i = blockIdx.x * 256 + threadIdx.x; i < total; i += gridDim.x * 256)
        out[i] = bias[i & 63];
}

// K3: per edge, exp(leaky_relu(si[r]+sj[c])) -> expalpha; atomic segment sum on row
__global__ __launch_bounds__(256) void k_edge1(
    const int* __restrict__ ei, const float* __restrict__ si,
    const float* __restrict__ sj, float* __restrict__ expalpha,
    float* __restrict__ segsum)
{
    const int e = blockIdx.x * 256 + threadIdx.x;
    if (e >= MT) return;
    int r, c;
    if (e < NE) { r = ei[e]; c = ei[NE + e]; } else { r = e - NE; c = r; }
    const float4 s1 = *(const float4*)(si + r * 4);
    const float4 s2 = *(const float4*)(sj + c * 4);
    float a[4] = { s1.x + s2.x, s1.y + s2.y, s1.z + s2.z, s1.w + s2.w };
    float4 ea;
    float* eap = &ea.x;
    #pragma unroll
    for (int hh = 0; hh < 4; ++hh) {
        float v = a[hh];
        v = v > 0.f ? v : NEG_SLOPE * v;
        const float ev = expf(v);
        eap[hh] = ev;
        atomicAdd(segsum + r * 4 + hh, ev);
    }
    *(float4*)(expalpha + e * 4) = ea;
}

// K4: one wave per edge: alpha = expalpha/segsum[row]; scatter-add messages to out[col];
//     accumulate the 10 unique alpha^T alpha entries (lane-0-canonical head order)
__global__ __launch_bounds__(256) void k_edge2(
    const int* __restrict__ ei, const float* __restrict__ expalpha,
    const float* __restrict__ segsum, const float* __restrict__ content,
    float* __restrict__ out, double* __restrict__ pairs)
{
    const int lane = threadIdx.x & 63;
    const int wid  = threadIdx.x >> 6;
    const int gw   = blockIdx.x * 4 + wid;
    const int nw   = gridDim.x * 4;
    const int h    = lane >> 4;
    float a0=0,a1=0,a2=0,a3=0,a4=0,a5=0,a6=0,a7=0,a8=0,a9=0;
    for (int e = gw; e < MT; e += nw) {
        int r, c;
        if (e < NE) { r = ei[e]; c = ei[NE + e]; } else { r = e - NE; c = r; }
        const float ea    = expalpha[e * 4 + h];
        const float ss    = segsum[r * 4 + h];
        const float alpha = ea / (ss + 1e-10f);
        const float cv    = content[r * HD + lane];
        atomicAdd(out + c * HD + lane, cv * alpha);   // coalesced 256B atomic
        const float v0 = alpha;
        const float v1 = __shfl_xor(alpha, 16);
        const float v2 = __shfl_xor(alpha, 32);
        const float v3 = __shfl_xor(alpha, 48);
        a0 = fmaf(v0, v0, a0); a1 = fmaf(v0, v1, a1); a2 = fmaf(v0, v2, a2);
        a3 = fmaf(v0, v3, a3); a4 = fmaf(v1, v1, a4); a5 = fmaf(v1, v2, a5);
        a6 = fmaf(v1, v3, a6); a7 = fmaf(v2, v2, a7); a8 = fmaf(v2, v3, a8);
        a9 = fmaf(v3, v3, a9);
    }
    __shared__ double red[4][10];
    if (lane == 0) {
        red[wid][0]=a0; red[wid][1]=a1; red[wid][2]=a2; red[wid][3]=a3; red[wid][4]=a4;
        red[wid][5]=a5; red[wid][6]=a6; red[wid][7]=a7; red[wid][8]=a8; red[wid][9]=a9;
    }
    __syncthreads();
    if (threadIdx.x < 10) {
        const double s = red[0][threadIdx.x] + red[1][threadIdx.x]
                       + red[2][threadIdx.x] + red[3][threadIdx.x];
        atomicAdd(pairs + threadIdx.x, s);
    }
}

// K5: finalize diversity loss from the 10 pair sums
__global__ void k_loss(const double* __restrict__ ps, float* __restrict__ out)
{
    if (threadIdx.x == 0 && blockIdx.x == 0) {
        const double s00=ps[0], s01=ps[1], s02=ps[2], s03=ps[3], s11=ps[4];
        const double s12=ps[5], s13=ps[6], s22=ps[7], s23=ps[8], s33=ps[9];
        const double n0 = fmax(sqrt(s00), 1e-12);
        const double n1 = fmax(sqrt(s11), 1e-12);
        const double n2 = fmax(sqrt(s22), 1e-12);
        const double n3 = fmax(sqrt(s33), 1e-12);
        double loss = 2.0 * ( s01/(n0*n1) + s02/(n0*n2) + s03/(n0*n3)
                            + s12/(n1*n2) + s13/(n1*n3) + s23/(n2*n3) );
        loss = loss / 16.0 * 0.1;
        out[NN * HD] = (float)loss;
    }
}

extern "C" void kernel_launch(void* const* d_in, const int* in_sizes, int n_in,
                              void* d_out, int out_size, void* d_ws, size_t ws_size,
                              hipStream_t stream)
{
    const float* x       = (const float*)d_in[0];
    const int*   ei      = (const int*)d_in[1];
    const float* W       = (const float*)d_in[2];
    const float* att     = (const float*)d_in[3];
    const float* pos_att = (const float*)d_in[4];
    const float* bias    = (const float*)d_in[5];
    float* out = (float*)d_out;

    // workspace layout (floats): content | si | sj | expalpha | segsum | pairs(10 f64)
    float* content  = (float*)d_ws;
    float* si       = content + (size_t)NN * HD;       // 6.4M
    float* sj       = si + (size_t)NN * HH;             // +0.4M
    float* expalpha = sj + (size_t)NN * HH;             // +0.4M
    float* segsum   = expalpha + (size_t)MT * HH;       // +5.2M
    double* pairs   = (double*)(segsum + (size_t)NN * HH); // 8B-aligned (51.2e6 % 8 == 0)

    hipMemsetAsync(segsum, 0, (size_t)NN * HH * sizeof(float) + 10 * sizeof(double), stream);
    k_init_out<<<2048, 256, 0, stream>>>(bias, out);
    k_content<<<2500, 256, 0, stream>>>(x, W, att, pos_att, content, si, sj);
    k_edge1<<<(MT + 255) / 256, 256, 0, stream>>>(ei, si, sj, expalpha, segsum);
    k_edge2<<<2048, 256, 0, stream>>>(ei, expalpha, segsum, content, out, pairs);
    k_loss<<<1, 64, 0, stream>>>(pairs, out);
}